// Round 5
// baseline (735.804 us; speedup 1.0000x reference)
//
#include <hip/hip_runtime.h>
#include <math.h>

// ---------------------------------------------------------------------------
// QuantumGenerator: ONE persistent kernel (1024 blocks x 256 threads,
// __launch_bounds__(256,4) => exactly 4 blocks/CU x 256 CU co-resident)
// + one 22KB hipMemsetAsync for barrier counters / BN partials.
// Hand-rolled grid barrier (no cooperative API -> graph-capturable):
//   release __threadfence() (agent-scope L2 writeback) -> atomicAdd arrival
//   -> spin on __hip_atomic_load ACQUIRE/AGENT with s_sleep backoff.
//   Spin is BOUNDED (50K) so a co-residency failure terminates diagnosably.
// BN stats: LDS bins -> slot-binned global atomics (32 slots/ch, <=32
// adds/address) -> consumer reduces its channel's 32 slots per-thread.
// Math: amplitude normalization cancels EXACTLY:
//   n = max(||x||,1e-9);  d = (Vx)^2 / max(S, 1e-9 * n^2),  n^2 = max(nsq,1e-18)
// (round-4 bug: used 1e-9*nsq -> 1/0 -> NaN on ReLU-zeroed patches).
// ---------------------------------------------------------------------------

#define NSLOT 32
#define NBLK  1024u

// ws float offsets
#define OFF_V    0        // 5440 floats
#define OFF_CTR  6144     // 8 uints (barrier counters)
#define OFF_G2S  6152     // 64*32
#define OFF_G2Q  8200     // 64*32
#define OFF_G3S  10248    // 16*32
#define OFF_G3Q  10760    // 16*32
#define OFF_G4S  11272    // 4*32
#define OFF_G4Q  11400    // 4*32
#define OFF_GFS  11528    // 1*32
#define OFF_GFQ  11560    // 1*32  (memset covers 6144..11592)

__device__ __forceinline__ void gbar(unsigned* ctr, int phase)
{
    __syncthreads();                       // all waves drained (waitcnt+s_barrier)
    if (threadIdx.x == 0){
        __threadfence();                   // release: wb L2 to LLC, agent scope
        unsigned* c = ctr + phase;
        atomicAdd(c, 1u);                  // device-scope arrival
        int spins = 0;
        while (__hip_atomic_load(c, __ATOMIC_ACQUIRE, __HIP_MEMORY_SCOPE_AGENT) < NBLK){
            __builtin_amdgcn_s_sleep(2);
            if (++spins > 50000) break;    // failsafe: terminate, not hang
        }
    }
    __syncthreads();                       // broadcast completion to block
}

__device__ __forceinline__ void build_V_dev(int t,
    const float* __restrict__ w1, const float* __restrict__ w2,
    const float* __restrict__ w3, const float* __restrict__ w4,
    float* __restrict__ V)
{
    const float* w; float* vout;
    if (t < 256)      { w = w1 + t*18;        vout = V + t*16; }
    else if (t < 320) { w = w2 + (t-256)*18;  vout = V + 4096 + (t-256)*16; }
    else if (t < 336) { w = w3 + (t-320)*18;  vout = V + 5120 + (t-320)*16; }
    else              { w = w4 + (t-336)*18;  vout = V + 5376 + (t-336)*16; }
    const int perm[8] = {0,5,7,2,3,6,4,1};   // CNOT ring: new[perm[r]] = old[r]
    float U[8][8];
    #pragma unroll
    for (int i=0;i<8;i++)
        #pragma unroll
        for (int j=0;j<8;j++) U[i][j] = (i==j) ? 1.0f : 0.0f;
    for (int l=0;l<6;l++){
        float c0 = cosf(0.5f*w[l*3+0]), s0 = sinf(0.5f*w[l*3+0]);
        float c1 = cosf(0.5f*w[l*3+1]), s1 = sinf(0.5f*w[l*3+1]);
        float c2 = cosf(0.5f*w[l*3+2]), s2 = sinf(0.5f*w[l*3+2]);
        #pragma unroll
        for (int col=0; col<8; col++){
            float v[8];
            #pragma unroll
            for (int r=0;r<8;r++) v[r] = U[r][col];
            #pragma unroll
            for (int b=0;b<8;b+=2){ float x=v[b], y=v[b+1]; v[b]=c2*x-s2*y; v[b+1]=s2*x+c2*y; }
            #pragma unroll
            for (int g=0;g<8;g+=4)
                #pragma unroll
                for (int i=0;i<2;i++){ int a=g+i, b=g+i+2; float x=v[a], y=v[b]; v[a]=c1*x-s1*y; v[b]=s1*x+c1*y; }
            #pragma unroll
            for (int i=0;i<4;i++){ float x=v[i], y=v[i+4]; v[i]=c0*x-s0*y; v[i+4]=s0*x+c0*y; }
            #pragma unroll
            for (int r=0;r<8;r++) U[perm[r]][col] = v[r];
        }
    }
    #pragma unroll
    for (int j=0;j<4;j++)
        #pragma unroll
        for (int k=0;k<4;k++) vout[j*4+k] = U[j][k];
}

template<int C, int H, int W, bool BN>
__device__ __forceinline__ void qcnn_phase(
    const float* __restrict__ x, const float* __restrict__ Vl,
    const float* __restrict__ isum, const float* __restrict__ issq,
    const float* __restrict__ gamma, const float* __restrict__ beta,
    float invNin,
    float* __restrict__ out, float* __restrict__ osum, float* __restrict__ ossq,
    float* sBin)
{
    constexpr int HW  = H*W;
    constexpr int P   = HW/4;                 // patches/channel: 4,16,64,256
    constexpr int OW  = W/2;
    constexpr int LP  = (P==4)?2:(P==16)?4:(P==64)?6:8;
    constexpr int LOW = (OW==2)?1:(OW==4)?2:(OW==8)?3:4;
    constexpr int CPB = 256/P;                // input channels per block
    constexpr int OCB = (CPB/4) < 1 ? 1 : (CPB/4);  // output BN bins per block
    constexpr int G   = (4*P < 64) ? 4*P : 64;      // lanes sharing one BN bin

    if (threadIdx.x < 2*OCB) sBin[threadIdx.x] = 0.0f;
    __syncthreads();

    const int r   = ((blockIdx.x & 3) << 8) + threadIdx.x;
    const int c   = r >> LP;
    const int p   = r & (P-1);
    const int oh  = p >> LOW;
    const int ow  = p & (OW-1);
    const int oc0 = ((blockIdx.x & 3) << 8) >> (LP+2);
    const int ocl = (r >> (LP+2)) - oc0;
    const int xoff = c*HW + (oh*2)*W + (ow*2);
    const int ooff = c*HW + (p<<2);

    float sc = 0.0f, sh = 0.0f;
    if constexpr (BN){
        // per-thread reduce of this channel's 32 partial slots (L1/L2-broadcast)
        float s = 0.0f, q = 0.0f;
        const float4* ps4 = reinterpret_cast<const float4*>(isum + c*NSLOT);
        const float4* pq4 = reinterpret_cast<const float4*>(issq + c*NSLOT);
        #pragma unroll
        for (int i=0;i<NSLOT/4;i++){
            float4 a = ps4[i], b = pq4[i];
            s += a.x+a.y+a.z+a.w;  q += b.x+b.y+b.z+b.w;
        }
        float mean = s * invNin;
        float var  = q * invNin - mean*mean;
        float rinv = 1.0f / sqrtf(var + 1e-5f);
        sc = gamma[c] * rinv;
        sh = beta[c] - mean * sc;
    }
    const float4* Vc = reinterpret_cast<const float4*>(Vl + c*16);
    const float4 v0 = Vc[0], v1 = Vc[1], v2 = Vc[2], v3 = Vc[3];

    #pragma unroll
    for (int it=0; it<4; ++it){
        const int b = (it<<8) + (blockIdx.x>>2);
        const float* xb = x + ((size_t)b<<12) + xoff;
        float2 t0 = *reinterpret_cast<const float2*>(xb);
        float2 t1 = *reinterpret_cast<const float2*>(xb + W);
        float x0=t0.x, x1=t0.y, x2=t1.x, x3=t1.y;
        if constexpr (BN){
            x0 = fmaxf(x0*sc+sh, 0.0f);
            x1 = fmaxf(x1*sc+sh, 0.0f);
            x2 = fmaxf(x2*sc+sh, 0.0f);
            x3 = fmaxf(x3*sc+sh, 0.0f);
        }
        // norm cancellation: n^2 = max(||x||^2, 1e-18); d = q^2/max(S, 1e-9*n^2)
        float nsq = x0*x0 + x1*x1 + x2*x2 + x3*x3;
        float q0 = v0.x*x0 + v0.y*x1 + v0.z*x2 + v0.w*x3;
        float q1 = v1.x*x0 + v1.y*x1 + v1.z*x2 + v1.w*x3;
        float q2 = v2.x*x0 + v2.y*x1 + v2.z*x2 + v2.w*x3;
        float q3 = v3.x*x0 + v3.y*x1 + v3.z*x2 + v3.w*x3;
        q0*=q0; q1*=q1; q2*=q2; q3*=q3;
        float s = q0+q1+q2+q3;
        float dinv = 1.0f / fmaxf(s, 1e-9f * fmaxf(nsq, 1e-18f));
        float d0=q0*dinv, d1=q1*dinv, d2=q2*dinv, d3=q3*dinv;
        *reinterpret_cast<float4*>(out + ((size_t)b<<12) + ooff) =
            make_float4(d0,d1,d2,d3);
        float ls  = d0+d1+d2+d3;
        float lss = d0*d0 + d1*d1 + d2*d2 + d3*d3;
        #pragma unroll
        for (int off=1; off<G; off<<=1){ ls += __shfl_xor(ls, off); lss += __shfl_xor(lss, off); }
        if ((threadIdx.x & (G-1)) == 0){
            atomicAdd(&sBin[ocl], ls);
            atomicAdd(&sBin[OCB + ocl], lss);
        }
    }
    __syncthreads();
    if (threadIdx.x < OCB){
        const int slot = (blockIdx.x >> 2) & (NSLOT-1);
        atomicAdd(&osum[(oc0+threadIdx.x)*NSLOT + slot], sBin[threadIdx.x]);
        atomicAdd(&ossq[(oc0+threadIdx.x)*NSLOT + slot], sBin[OCB+threadIdx.x]);
    }
}

__global__ __launch_bounds__(256, 4) void fused_all(
    const float* __restrict__ z,
    const float* __restrict__ w1, const float* __restrict__ w2,
    const float* __restrict__ w3, const float* __restrict__ w4,
    const float* __restrict__ gamma2, const float* __restrict__ beta2,
    const float* __restrict__ gamma3, const float* __restrict__ beta3,
    const float* __restrict__ gamma4, const float* __restrict__ beta4,
    const float* __restrict__ gammaf, const float* __restrict__ betaf,
    float* __restrict__ out, float* __restrict__ ws)
{
    __shared__ float sBin[32];
    unsigned* ctr = reinterpret_cast<unsigned*>(ws + OFF_CTR);
    float* V    = ws + OFF_V;
    float* bufA = ws + 65536;                 // 4M floats (s1, then s3)
    float* bufB = bufA + 4194304;             // 4M floats (s2)
    float* s4   = out + 4194304;              // output slot 1
    float* s4bn = out + 8388608;              // output slot 2
    const int gtid = blockIdx.x*256 + threadIdx.x;

    // P0: unitaries (blocks 0-1 only; others arrive at barrier immediately)
    if (gtid < 340) build_V_dev(gtid, w1, w2, w3, w4, V);
    gbar(ctr, 0);

    // P1: L1  z(1024,256,4,4) -> s1(bufA); stats -> g2 (64 ch, N=65536)
    qcnn_phase<256,4,4,false>(z, V, nullptr, nullptr, nullptr, nullptr, 0.0f,
                              bufA, ws+OFF_G2S, ws+OFF_G2Q, sBin);
    gbar(ctr, 1);

    // P2: L2  relu(bn(s1)) -> s2(bufB); stats -> g3 (16 ch, N=262144)
    qcnn_phase<64,8,8,true>(bufA, V+4096, ws+OFF_G2S, ws+OFF_G2Q, gamma2, beta2,
                            1.0f/65536.0f, bufB, ws+OFF_G3S, ws+OFF_G3Q, sBin);
    gbar(ctr, 2);

    // P3: L3 -> s3(bufA); stats -> g4 (4 ch, N=1048576)
    qcnn_phase<16,16,16,true>(bufB, V+5120, ws+OFF_G3S, ws+OFF_G3Q, gamma3, beta3,
                              1.0f/262144.0f, bufA, ws+OFF_G4S, ws+OFF_G4Q, sBin);
    gbar(ctr, 3);

    // P4: L4 -> s4 (out slot 1); stats -> gf (1 ch, N=4194304)
    qcnn_phase<4,32,32,true>(bufA, V+5376, ws+OFF_G4S, ws+OFF_G4Q, gamma4, beta4,
                             1.0f/1048576.0f, s4, ws+OFF_GFS, ws+OFF_GFQ, sBin);
    gbar(ctr, 4);

    // P5: final  s4_bn -> out slot 2, tanh -> out slot 0
    {
        float s = 0.0f, q = 0.0f;
        const float4* ps4 = reinterpret_cast<const float4*>(ws + OFF_GFS);
        const float4* pq4 = reinterpret_cast<const float4*>(ws + OFF_GFQ);
        #pragma unroll
        for (int i=0;i<NSLOT/4;i++){
            float4 a = ps4[i], b = pq4[i];
            s += a.x+a.y+a.z+a.w;  q += b.x+b.y+b.z+b.w;
        }
        float mean = s * (1.0f/4194304.0f);
        float var  = q * (1.0f/4194304.0f) - mean*mean;
        float rinv = 1.0f / sqrtf(var + 1e-5f);
        float sc = gammaf[0]*rinv;
        float sh = betaf[0] - mean*sc;
        #pragma unroll
        for (int k=0; k<4; ++k){
            int i = gtid + k*262144;                     // 1M float4s
            float4 v = reinterpret_cast<const float4*>(s4)[i];
            float4 bn = make_float4(v.x*sc+sh, v.y*sc+sh, v.z*sc+sh, v.w*sc+sh);
            reinterpret_cast<float4*>(s4bn)[i] = bn;
            reinterpret_cast<float4*>(out)[i] =
                make_float4(tanhf(bn.x), tanhf(bn.y), tanhf(bn.z), tanhf(bn.w));
        }
    }
}

extern "C" void kernel_launch(void* const* d_in, const int* in_sizes, int n_in,
                              void* d_out, int out_size, void* d_ws, size_t ws_size,
                              hipStream_t stream)
{
    const float* z      = (const float*)d_in[0];
    const float* w1     = (const float*)d_in[1];
    const float* w2     = (const float*)d_in[2];
    const float* w3     = (const float*)d_in[3];
    const float* w4     = (const float*)d_in[4];
    const float* gamma2 = (const float*)d_in[5];
    const float* beta2  = (const float*)d_in[6];
    const float* gamma3 = (const float*)d_in[7];
    const float* beta3  = (const float*)d_in[8];
    const float* gamma4 = (const float*)d_in[9];
    const float* beta4  = (const float*)d_in[10];
    const float* gammaf = (const float*)d_in[11];
    const float* betaf  = (const float*)d_in[12];
    float* out = (float*)d_out;
    float* ws  = (float*)d_ws;

    // zero barrier counters + BN partial slots (poisoned each iteration)
    hipMemsetAsync(ws + OFF_CTR, 0, (8 + 5440) * sizeof(float), stream);

    fused_all<<<1024, 256, 0, stream>>>(
        z, w1, w2, w3, w4, gamma2, beta2, gamma3, beta3,
        gamma4, beta4, gammaf, betaf, out, ws);
}

// Round 6
// 286.784 us; speedup vs baseline: 2.5657x; 2.5657x over previous
//
#include <hip/hip_runtime.h>
#include <math.h>

// ---------------------------------------------------------------------------
// QuantumGenerator: ONE persistent kernel (1024 blocks x 256 threads,
// __launch_bounds__(256,4) => 4 blocks/CU x 256 CU co-resident) + one memset.
//
// Grid barrier v2 (round-5's flat barrier cost ~100us each; this one ~5us):
//   - two-level arrival: RELEASE atomicAdd into 32 leaf counters (64B apart,
//     <=32 serialized adds each, leaves parallel); last leaf-arriver bumps
//     root (32 adds).  [kills the 1024-same-address serialization]
//   - poll root with RELAXED agent loads (LLC-coherent, NO buffer_inv per
//     poll) + s_sleep backoff; ONE acquire load per block after exit gives
//     the L2 invalidate.  [kills the inv-storm that also thrashed late
//     blocks' L2 working sets]
//   - spin bounded -> co-residency failure terminates diagnosably.
//
// build_V phase eliminated: unitary COLUMNS evolve independently and only
// cols 0-3 are used, so each block computes its own channels' 4 columns into
// LDS (<=256 threads, ~0.3us) -> 4 barriers instead of 5, no V global trip.
//
// BN stats: LDS bins -> slot-binned global atomics (32 slots/ch) -> consumer
// reduces slots per-thread.  Norm cancellation (exact):
//   n^2 = max(||x||^2, 1e-18);  d = (Vx)^2 / max(S, 1e-9*n^2)
// ---------------------------------------------------------------------------

#define NSLOT 32
#define NBLK  1024u

// ws float offsets
#define OFF_G2S 0        // 64*32
#define OFF_G2Q 2048     // 64*32
#define OFF_G3S 4096     // 16*32
#define OFF_G3Q 4608     // 16*32
#define OFF_G4S 5120     // 4*32
#define OFF_G4Q 5248     // 4*32
#define OFF_GFS 5376     // 1*32
#define OFF_GFQ 5408     // 1*32
#define OFF_CTR 5504     // 4 phases x 544 uints (leaves 64B apart + root)
// memset covers [0 .. 7680) floats

__device__ __forceinline__ void gbar(unsigned* ctr, int phase)
{
    __syncthreads();                        // all waves of block drained
    if (threadIdx.x == 0){
        unsigned* base = ctr + phase*544;
        unsigned* leaf = base + ((blockIdx.x & 31) << 4);   // 64B apart
        unsigned* root = base + 528;
        // release-add: prior (phase) stores flushed before arrival visible
        unsigned old = __hip_atomic_fetch_add(leaf, 1u, __ATOMIC_RELEASE,
                                              __HIP_MEMORY_SCOPE_AGENT);
        if (old == 31u)
            __hip_atomic_fetch_add(root, 1u, __ATOMIC_RELAXED,
                                   __HIP_MEMORY_SCOPE_AGENT);
        int spins = 0;
        while (__hip_atomic_load(root, __ATOMIC_RELAXED,
                                 __HIP_MEMORY_SCOPE_AGENT) < 32u){
            __builtin_amdgcn_s_sleep(4);
            if (++spins > 100000) break;    // failsafe: terminate, not hang
        }
        // single acquire -> L2 invalidate so we see other XCDs' data
        __hip_atomic_load(root, __ATOMIC_ACQUIRE, __HIP_MEMORY_SCOPE_AGENT);
    }
    __syncthreads();
}

template<int C, int H, int W, bool BN>
__device__ __forceinline__ void qcnn_phase(
    const float* __restrict__ x, const float* __restrict__ wl,
    const float* __restrict__ isum, const float* __restrict__ issq,
    const float* __restrict__ gamma, const float* __restrict__ beta,
    float invNin,
    float* __restrict__ out, float* __restrict__ osum, float* __restrict__ ossq,
    float* sBin, float* sV)
{
    constexpr int HW  = H*W;
    constexpr int P   = HW/4;                 // patches/channel: 4,16,64,256
    constexpr int OW  = W/2;
    constexpr int LP  = (P==4)?2:(P==16)?4:(P==64)?6:8;
    constexpr int LOW = (OW==2)?1:(OW==4)?2:(OW==8)?3:4;
    constexpr int CPB = 256/P;                // input channels per block
    constexpr int OCB = (CPB/4) < 1 ? 1 : (CPB/4);  // output BN bins per block
    constexpr int G   = (4*P < 64) ? 4*P : 64;      // lanes sharing one BN bin

    const int c0 = (blockIdx.x & 3) * CPB;

    // ---- build this block's V channels (cols 0-3 only) into LDS ----
    if (threadIdx.x < CPB*4){
        const int cl = threadIdx.x >> 2;      // local channel
        const int k  = threadIdx.x & 2|(threadIdx.x&1); // = threadIdx.x & 3
        const float* w = wl + (c0+cl)*18;
        float v[8];
        #pragma unroll
        for (int r=0;r<8;r++) v[r] = (r==k) ? 1.0f : 0.0f;
        for (int l=0;l<6;l++){
            float ca = cosf(0.5f*w[l*3+0]), sa = sinf(0.5f*w[l*3+0]);
            float cb = cosf(0.5f*w[l*3+1]), sb = sinf(0.5f*w[l*3+1]);
            float cc = cosf(0.5f*w[l*3+2]), sc_ = sinf(0.5f*w[l*3+2]);
            #pragma unroll
            for (int b=0;b<8;b+=2){ float xx=v[b], yy=v[b+1]; v[b]=cc*xx-sc_*yy; v[b+1]=sc_*xx+cc*yy; }
            #pragma unroll
            for (int g=0; g<8; g+=4)
                #pragma unroll
                for (int i=0;i<2;i++){ int a=g+i, b=g+i+2; float xx=v[a], yy=v[b]; v[a]=cb*xx-sb*yy; v[b]=sb*xx+cb*yy; }
            #pragma unroll
            for (int i=0;i<4;i++){ float xx=v[i], yy=v[i+4]; v[i]=ca*xx-sa*yy; v[i+4]=sa*xx+ca*yy; }
            // CNOT ring: new[perm[r]] = old[r]; perm = {0,5,7,2,3,6,4,1}
            float nv[8];
            nv[0]=v[0]; nv[5]=v[1]; nv[7]=v[2]; nv[2]=v[3];
            nv[3]=v[4]; nv[6]=v[5]; nv[4]=v[6]; nv[1]=v[7];
            #pragma unroll
            for (int r=0;r<8;r++) v[r]=nv[r];
        }
        #pragma unroll
        for (int r=0;r<4;r++) sV[cl*16 + r*4 + k] = v[r];   // U[r][k]
    }
    if (threadIdx.x < 2*OCB) sBin[threadIdx.x] = 0.0f;
    __syncthreads();

    const int r   = ((blockIdx.x & 3) << 8) + threadIdx.x;
    const int c   = r >> LP;
    const int p   = r & (P-1);
    const int oh  = p >> LOW;
    const int ow  = p & (OW-1);
    const int oc0 = ((blockIdx.x & 3) << 8) >> (LP+2);
    const int ocl = (r >> (LP+2)) - oc0;
    const int xoff = c*HW + (oh*2)*W + (ow*2);
    const int ooff = c*HW + (p<<2);

    float sc = 0.0f, sh = 0.0f;
    if constexpr (BN){
        // per-thread reduce of this channel's 32 partial slots (broadcast loads)
        float s = 0.0f, q = 0.0f;
        const float4* ps4 = reinterpret_cast<const float4*>(isum + c*NSLOT);
        const float4* pq4 = reinterpret_cast<const float4*>(issq + c*NSLOT);
        #pragma unroll
        for (int i=0;i<NSLOT/4;i++){
            float4 a = ps4[i], b = pq4[i];
            s += a.x+a.y+a.z+a.w;  q += b.x+b.y+b.z+b.w;
        }
        float mean = s * invNin;
        float var  = q * invNin - mean*mean;
        float rinv = 1.0f / sqrtf(var + 1e-5f);
        sc = gamma[c] * rinv;
        sh = beta[c] - mean * sc;
    }
    const float4* Vc = reinterpret_cast<const float4*>(sV + (c-c0)*16);
    const float4 v0 = Vc[0], v1 = Vc[1], v2 = Vc[2], v3 = Vc[3];

    #pragma unroll
    for (int it=0; it<4; ++it){
        const int b = (it<<8) + (blockIdx.x>>2);
        const float* xb = x + ((size_t)b<<12) + xoff;
        float2 t0 = *reinterpret_cast<const float2*>(xb);
        float2 t1 = *reinterpret_cast<const float2*>(xb + W);
        float x0=t0.x, x1=t0.y, x2=t1.x, x3=t1.y;
        if constexpr (BN){
            x0 = fmaxf(x0*sc+sh, 0.0f);
            x1 = fmaxf(x1*sc+sh, 0.0f);
            x2 = fmaxf(x2*sc+sh, 0.0f);
            x3 = fmaxf(x3*sc+sh, 0.0f);
        }
        float nsq = x0*x0 + x1*x1 + x2*x2 + x3*x3;
        float q0 = v0.x*x0 + v0.y*x1 + v0.z*x2 + v0.w*x3;
        float q1 = v1.x*x0 + v1.y*x1 + v1.z*x2 + v1.w*x3;
        float q2 = v2.x*x0 + v2.y*x1 + v2.z*x2 + v2.w*x3;
        float q3 = v3.x*x0 + v3.y*x1 + v3.z*x2 + v3.w*x3;
        q0*=q0; q1*=q1; q2*=q2; q3*=q3;
        float s = q0+q1+q2+q3;
        float dinv = 1.0f / fmaxf(s, 1e-9f * fmaxf(nsq, 1e-18f));
        float d0=q0*dinv, d1=q1*dinv, d2=q2*dinv, d3=q3*dinv;
        *reinterpret_cast<float4*>(out + ((size_t)b<<12) + ooff) =
            make_float4(d0,d1,d2,d3);
        float ls  = d0+d1+d2+d3;
        float lss = d0*d0 + d1*d1 + d2*d2 + d3*d3;
        #pragma unroll
        for (int off=1; off<G; off<<=1){ ls += __shfl_xor(ls, off); lss += __shfl_xor(lss, off); }
        if ((threadIdx.x & (G-1)) == 0){
            atomicAdd(&sBin[ocl], ls);
            atomicAdd(&sBin[OCB + ocl], lss);
        }
    }
    __syncthreads();
    if (threadIdx.x < OCB){
        const int slot = (blockIdx.x >> 2) & (NSLOT-1);
        atomicAdd(&osum[(oc0+threadIdx.x)*NSLOT + slot], sBin[threadIdx.x]);
        atomicAdd(&ossq[(oc0+threadIdx.x)*NSLOT + slot], sBin[OCB+threadIdx.x]);
    }
}

__global__ __launch_bounds__(256, 4) void fused_all(
    const float* __restrict__ z,
    const float* __restrict__ w1, const float* __restrict__ w2,
    const float* __restrict__ w3, const float* __restrict__ w4,
    const float* __restrict__ gamma2, const float* __restrict__ beta2,
    const float* __restrict__ gamma3, const float* __restrict__ beta3,
    const float* __restrict__ gamma4, const float* __restrict__ beta4,
    const float* __restrict__ gammaf, const float* __restrict__ betaf,
    float* __restrict__ out, float* __restrict__ ws)
{
    __shared__ float sBin[32];
    __shared__ float sV[1024];                // up to 64 ch x 16 floats
    unsigned* ctr = reinterpret_cast<unsigned*>(ws + OFF_CTR);
    float* bufA = ws + 65536;                 // 4M floats (s1, then s3)
    float* bufB = bufA + 4194304;             // 4M floats (s2)
    float* s4   = out + 4194304;              // output slot 1
    float* s4bn = out + 8388608;              // output slot 2
    const int gtid = blockIdx.x*256 + threadIdx.x;

    // P1: L1  z(1024,256,4,4) -> s1(bufA); stats -> g2 (64 ch, N=65536)
    qcnn_phase<256,4,4,false>(z, w1, nullptr, nullptr, nullptr, nullptr, 0.0f,
                              bufA, ws+OFF_G2S, ws+OFF_G2Q, sBin, sV);
    gbar(ctr, 0);

    // P2: L2  relu(bn(s1)) -> s2(bufB); stats -> g3 (16 ch, N=262144)
    qcnn_phase<64,8,8,true>(bufA, w2, ws+OFF_G2S, ws+OFF_G2Q, gamma2, beta2,
                            1.0f/65536.0f, bufB, ws+OFF_G3S, ws+OFF_G3Q, sBin, sV);
    gbar(ctr, 1);

    // P3: L3 -> s3(bufA); stats -> g4 (4 ch, N=1048576)
    qcnn_phase<16,16,16,true>(bufB, w3, ws+OFF_G3S, ws+OFF_G3Q, gamma3, beta3,
                              1.0f/262144.0f, bufA, ws+OFF_G4S, ws+OFF_G4Q, sBin, sV);
    gbar(ctr, 2);

    // P4: L4 -> s4 (out slot 1); stats -> gf (1 ch, N=4194304)
    qcnn_phase<4,32,32,true>(bufA, w4, ws+OFF_G4S, ws+OFF_G4Q, gamma4, beta4,
                             1.0f/1048576.0f, s4, ws+OFF_GFS, ws+OFF_GFQ, sBin, sV);
    gbar(ctr, 3);

    // P5: final  s4_bn -> out slot 2, tanh -> out slot 0
    {
        float s = 0.0f, q = 0.0f;
        const float4* ps4 = reinterpret_cast<const float4*>(ws + OFF_GFS);
        const float4* pq4 = reinterpret_cast<const float4*>(ws + OFF_GFQ);
        #pragma unroll
        for (int i=0;i<NSLOT/4;i++){
            float4 a = ps4[i], b = pq4[i];
            s += a.x+a.y+a.z+a.w;  q += b.x+b.y+b.z+b.w;
        }
        float mean = s * (1.0f/4194304.0f);
        float var  = q * (1.0f/4194304.0f) - mean*mean;
        float rinv = 1.0f / sqrtf(var + 1e-5f);
        float sc = gammaf[0]*rinv;
        float sh = betaf[0] - mean*sc;
        #pragma unroll
        for (int k=0; k<4; ++k){
            int i = gtid + k*262144;                     // 1M float4s
            float4 v = reinterpret_cast<const float4*>(s4)[i];
            float4 bn = make_float4(v.x*sc+sh, v.y*sc+sh, v.z*sc+sh, v.w*sc+sh);
            reinterpret_cast<float4*>(s4bn)[i] = bn;
            reinterpret_cast<float4*>(out)[i] =
                make_float4(tanhf(bn.x), tanhf(bn.y), tanhf(bn.z), tanhf(bn.w));
        }
    }
}

extern "C" void kernel_launch(void* const* d_in, const int* in_sizes, int n_in,
                              void* d_out, int out_size, void* d_ws, size_t ws_size,
                              hipStream_t stream)
{
    const float* z      = (const float*)d_in[0];
    const float* w1     = (const float*)d_in[1];
    const float* w2     = (const float*)d_in[2];
    const float* w3     = (const float*)d_in[3];
    const float* w4     = (const float*)d_in[4];
    const float* gamma2 = (const float*)d_in[5];
    const float* beta2  = (const float*)d_in[6];
    const float* gamma3 = (const float*)d_in[7];
    const float* beta3  = (const float*)d_in[8];
    const float* gamma4 = (const float*)d_in[9];
    const float* beta4  = (const float*)d_in[10];
    const float* gammaf = (const float*)d_in[11];
    const float* betaf  = (const float*)d_in[12];
    float* out = (float*)d_out;
    float* ws  = (float*)d_ws;

    // zero BN partial slots + barrier counters
    hipMemsetAsync(ws, 0, 7680 * sizeof(float), stream);

    fused_all<<<1024, 256, 0, stream>>>(
        z, w1, w2, w3, w4, gamma2, beta2, gamma3, beta3,
        gamma4, beta4, gammaf, betaf, out, ws);
}

// Round 7
// 190.077 us; speedup vs baseline: 3.8711x; 1.5088x over previous
//
#include <hip/hip_runtime.h>
#include <math.h>

// ---------------------------------------------------------------------------
// QuantumGenerator: ONE persistent kernel (1024 blocks x 256 threads,
// __launch_bounds__(256,4) => 4 blocks/CU x 256 CU co-resident) + one memset.
//
// KEY INVARIANT (verified for all phase transitions, incl. final):
//   block bid's phase-N+1 reads come EXACTLY from block bid's phase-N writes
//   (batch stride = 4096 floats at every layer; CPB*HW = 1024 at every layer;
//   both producer and consumer of block bid cover floats
//   [1024*(bid&3), +1024) of batches b = (it<<8)+(bid>>2)).
//   A block never migrates -> its own stores are visible via its own L1/L2.
//   ONLY cross-block data: BN partial sums (<=4KB), written by device-scope
//   atomicAdd (performed at coherent LLC), read by RELAXED agent atomic loads.
//
// Grid barrier v3 — NO cache maintenance at all (round-6 cost ~40us/barrier
// was 128 wbl2 + 128 buffer_inv serializing per XCD L2):
//   syncthreads (drains vmcnt => stats atomics performed at LLC)
//   -> relaxed leaf(32, 64B apart)/root arrival tree -> relaxed spin
//   -> compiler-only acquire fence.  Bounded spin => diagnosable failure.
//
// Norm cancellation (exact): n^2 = max(||x||^2,1e-18); d=(Vx)^2/max(S,1e-9*n^2)
// Per-block V build in LDS (cols 0-3 of the 8x8 unitary only).
// ---------------------------------------------------------------------------

#define NSLOT 32
#define NBLK  1024u

// ws float offsets
#define OFF_G2S 0        // 64*32
#define OFF_G2Q 2048     // 64*32
#define OFF_G3S 4096     // 16*32
#define OFF_G3Q 4608     // 16*32
#define OFF_G4S 5120     // 4*32
#define OFF_G4Q 5248     // 4*32
#define OFF_GFS 5376     // 1*32
#define OFF_GFQ 5408     // 1*32
#define OFF_CTR 5504     // 4 phases x 544 uints (32 leaves 64B apart + root)
// memset covers [0 .. 7680) floats

__device__ __forceinline__ void gbar(unsigned* ctr, int phase)
{
    __syncthreads();   // waitcnt vmcnt(0)+barrier: block's stats atomics performed
    if (threadIdx.x == 0){
        unsigned* base = ctr + phase*544;
        unsigned* leaf = base + ((blockIdx.x & 31) << 4);   // 64B apart
        unsigned* root = base + 528;
        unsigned old = __hip_atomic_fetch_add(leaf, 1u, __ATOMIC_RELAXED,
                                              __HIP_MEMORY_SCOPE_AGENT);
        if (old == 31u)
            __hip_atomic_fetch_add(root, 1u, __ATOMIC_RELAXED,
                                   __HIP_MEMORY_SCOPE_AGENT);
        int spins = 0;
        while (__hip_atomic_load(root, __ATOMIC_RELAXED,
                                 __HIP_MEMORY_SCOPE_AGENT) < 32u){
            __builtin_amdgcn_s_sleep(2);
            if (++spins > 200000) break;    // failsafe: terminate, not hang
        }
        __atomic_signal_fence(__ATOMIC_SEQ_CST);  // compiler fence only
    }
    __syncthreads();
}

// read a BN partial slot from the coherent LLC (bypasses stale L1/L2)
__device__ __forceinline__ float llc_load(const float* p)
{
    return __hip_atomic_load(const_cast<float*>(p), __ATOMIC_RELAXED,
                             __HIP_MEMORY_SCOPE_AGENT);
}

template<int C, int H, int W, bool BN>
__device__ __forceinline__ void qcnn_phase(
    const float* __restrict__ x, const float* __restrict__ wl,
    const float* __restrict__ isum, const float* __restrict__ issq,
    const float* __restrict__ gamma, const float* __restrict__ beta,
    float invNin,
    float* __restrict__ out, float* __restrict__ osum, float* __restrict__ ossq,
    float* sBin, float* sV)
{
    constexpr int HW  = H*W;
    constexpr int P   = HW/4;                 // patches/channel: 4,16,64,256
    constexpr int OW  = W/2;
    constexpr int LP  = (P==4)?2:(P==16)?4:(P==64)?6:8;
    constexpr int LOW = (OW==2)?1:(OW==4)?2:(OW==8)?3:4;
    constexpr int CPB = 256/P;                // input channels per block
    constexpr int OCB = (CPB/4) < 1 ? 1 : (CPB/4);  // output BN bins per block
    constexpr int G   = (4*P < 64) ? 4*P : 64;      // lanes sharing one BN bin

    const int c0 = (blockIdx.x & 3) * CPB;

    // ---- build this block's V channels (cols 0-3 only) into LDS ----
    if (threadIdx.x < CPB*4){
        const int cl = threadIdx.x >> 2;      // local channel
        const int k  = threadIdx.x & 3;       // column 0..3
        const float* w = wl + (c0+cl)*18;
        float v[8];
        #pragma unroll
        for (int r=0;r<8;r++) v[r] = (r==k) ? 1.0f : 0.0f;
        for (int l=0;l<6;l++){
            float ca = cosf(0.5f*w[l*3+0]), sa = sinf(0.5f*w[l*3+0]);
            float cb = cosf(0.5f*w[l*3+1]), sb = sinf(0.5f*w[l*3+1]);
            float cc = cosf(0.5f*w[l*3+2]), sc_ = sinf(0.5f*w[l*3+2]);
            #pragma unroll
            for (int b=0;b<8;b+=2){ float xx=v[b], yy=v[b+1]; v[b]=cc*xx-sc_*yy; v[b+1]=sc_*xx+cc*yy; }
            #pragma unroll
            for (int g=0; g<8; g+=4)
                #pragma unroll
                for (int i=0;i<2;i++){ int a=g+i, b=g+i+2; float xx=v[a], yy=v[b]; v[a]=cb*xx-sb*yy; v[b]=sb*xx+cb*yy; }
            #pragma unroll
            for (int i=0;i<4;i++){ float xx=v[i], yy=v[i+4]; v[i]=ca*xx-sa*yy; v[i+4]=sa*xx+ca*yy; }
            // CNOT ring: new[perm[r]] = old[r]; perm = {0,5,7,2,3,6,4,1}
            float nv[8];
            nv[0]=v[0]; nv[5]=v[1]; nv[7]=v[2]; nv[2]=v[3];
            nv[3]=v[4]; nv[6]=v[5]; nv[4]=v[6]; nv[1]=v[7];
            #pragma unroll
            for (int r=0;r<8;r++) v[r]=nv[r];
        }
        #pragma unroll
        for (int r=0;r<4;r++) sV[cl*16 + r*4 + k] = v[r];   // U[r][k]
    }
    if (threadIdx.x < 2*OCB) sBin[threadIdx.x] = 0.0f;
    __syncthreads();

    const int r   = ((blockIdx.x & 3) << 8) + threadIdx.x;
    const int c   = r >> LP;
    const int p   = r & (P-1);
    const int oh  = p >> LOW;
    const int ow  = p & (OW-1);
    const int oc0 = ((blockIdx.x & 3) << 8) >> (LP+2);
    const int ocl = (r >> (LP+2)) - oc0;
    const int xoff = c*HW + (oh*2)*W + (ow*2);
    const int ooff = c*HW + (p<<2);

    float sc = 0.0f, sh = 0.0f;
    if constexpr (BN){
        // reduce this channel's 32 partial slots from the LLC (cross-block data)
        float s = 0.0f, q = 0.0f;
        const float* ps = isum + c*NSLOT;
        const float* pq = issq + c*NSLOT;
        #pragma unroll
        for (int i=0;i<NSLOT;i++){ s += llc_load(ps+i); q += llc_load(pq+i); }
        float mean = s * invNin;
        float var  = q * invNin - mean*mean;
        float rinv = 1.0f / sqrtf(var + 1e-5f);
        sc = gamma[c] * rinv;
        sh = beta[c] - mean * sc;
    }
    const float4* Vc = reinterpret_cast<const float4*>(sV + (c-c0)*16);
    const float4 v0 = Vc[0], v1 = Vc[1], v2 = Vc[2], v3 = Vc[3];

    #pragma unroll
    for (int it=0; it<4; ++it){
        const int b = (it<<8) + (blockIdx.x>>2);
        const float* xb = x + ((size_t)b<<12) + xoff;
        float2 t0 = *reinterpret_cast<const float2*>(xb);
        float2 t1 = *reinterpret_cast<const float2*>(xb + W);
        float x0=t0.x, x1=t0.y, x2=t1.x, x3=t1.y;
        if constexpr (BN){
            x0 = fmaxf(x0*sc+sh, 0.0f);
            x1 = fmaxf(x1*sc+sh, 0.0f);
            x2 = fmaxf(x2*sc+sh, 0.0f);
            x3 = fmaxf(x3*sc+sh, 0.0f);
        }
        float nsq = x0*x0 + x1*x1 + x2*x2 + x3*x3;
        float q0 = v0.x*x0 + v0.y*x1 + v0.z*x2 + v0.w*x3;
        float q1 = v1.x*x0 + v1.y*x1 + v1.z*x2 + v1.w*x3;
        float q2 = v2.x*x0 + v2.y*x1 + v2.z*x2 + v2.w*x3;
        float q3 = v3.x*x0 + v3.y*x1 + v3.z*x2 + v3.w*x3;
        q0*=q0; q1*=q1; q2*=q2; q3*=q3;
        float s = q0+q1+q2+q3;
        float dinv = 1.0f / fmaxf(s, 1e-9f * fmaxf(nsq, 1e-18f));
        float d0=q0*dinv, d1=q1*dinv, d2=q2*dinv, d3=q3*dinv;
        *reinterpret_cast<float4*>(out + ((size_t)b<<12) + ooff) =
            make_float4(d0,d1,d2,d3);
        float ls  = d0+d1+d2+d3;
        float lss = d0*d0 + d1*d1 + d2*d2 + d3*d3;
        #pragma unroll
        for (int off=1; off<G; off<<=1){ ls += __shfl_xor(ls, off); lss += __shfl_xor(lss, off); }
        if ((threadIdx.x & (G-1)) == 0){
            atomicAdd(&sBin[ocl], ls);
            atomicAdd(&sBin[OCB + ocl], lss);
        }
    }
    __syncthreads();
    if (threadIdx.x < OCB){
        const int slot = (blockIdx.x >> 2) & (NSLOT-1);
        atomicAdd(&osum[(oc0+threadIdx.x)*NSLOT + slot], sBin[threadIdx.x]);
        atomicAdd(&ossq[(oc0+threadIdx.x)*NSLOT + slot], sBin[OCB+threadIdx.x]);
    }
}

__global__ __launch_bounds__(256, 4) void fused_all(
    const float* __restrict__ z,
    const float* __restrict__ w1, const float* __restrict__ w2,
    const float* __restrict__ w3, const float* __restrict__ w4,
    const float* __restrict__ gamma2, const float* __restrict__ beta2,
    const float* __restrict__ gamma3, const float* __restrict__ beta3,
    const float* __restrict__ gamma4, const float* __restrict__ beta4,
    const float* __restrict__ gammaf, const float* __restrict__ betaf,
    float* __restrict__ out, float* __restrict__ ws)
{
    __shared__ float sBin[32];
    __shared__ float sV[1024];                // up to 64 ch x 16 floats
    unsigned* ctr = reinterpret_cast<unsigned*>(ws + OFF_CTR);
    float* bufA = ws + 65536;                 // 4M floats (s1, then s3)
    float* bufB = bufA + 4194304;             // 4M floats (s2)
    float* s4   = out + 4194304;              // output slot 1
    float* s4bn = out + 8388608;              // output slot 2
    const int gtid = blockIdx.x*256 + threadIdx.x;

    // P1: L1  z(1024,256,4,4) -> s1(bufA); stats -> g2 (64 ch, N=65536)
    qcnn_phase<256,4,4,false>(z, w1, nullptr, nullptr, nullptr, nullptr, 0.0f,
                              bufA, ws+OFF_G2S, ws+OFF_G2Q, sBin, sV);
    gbar(ctr, 0);

    // P2: L2  relu(bn(s1)) -> s2(bufB); stats -> g3 (16 ch, N=262144)
    qcnn_phase<64,8,8,true>(bufA, w2, ws+OFF_G2S, ws+OFF_G2Q, gamma2, beta2,
                            1.0f/65536.0f, bufB, ws+OFF_G3S, ws+OFF_G3Q, sBin, sV);
    gbar(ctr, 1);

    // P3: L3 -> s3(bufA); stats -> g4 (4 ch, N=1048576)
    qcnn_phase<16,16,16,true>(bufB, w3, ws+OFF_G3S, ws+OFF_G3Q, gamma3, beta3,
                              1.0f/262144.0f, bufA, ws+OFF_G4S, ws+OFF_G4Q, sBin, sV);
    gbar(ctr, 2);

    // P4: L4 -> s4 (out slot 1); stats -> gf (1 ch, N=4194304)
    qcnn_phase<4,32,32,true>(bufA, w4, ws+OFF_G4S, ws+OFF_G4Q, gamma4, beta4,
                             1.0f/1048576.0f, s4, ws+OFF_GFS, ws+OFF_GFQ, sBin, sV);
    gbar(ctr, 3);

    // P5: final  s4_bn -> out slot 2, tanh -> out slot 0  (reads OWN s4 region)
    {
        float s = 0.0f, q = 0.0f;
        const float* ps = ws + OFF_GFS;
        const float* pq = ws + OFF_GFQ;
        #pragma unroll
        for (int i=0;i<NSLOT;i++){ s += llc_load(ps+i); q += llc_load(pq+i); }
        float mean = s * (1.0f/4194304.0f);
        float var  = q * (1.0f/4194304.0f) - mean*mean;
        float rinv = 1.0f / sqrtf(var + 1e-5f);
        float sc = gammaf[0]*rinv;
        float sh = betaf[0] - mean*sc;
        #pragma unroll
        for (int k=0; k<4; ++k){
            int i = gtid + k*262144;                     // 1M float4s
            float4 v = reinterpret_cast<const float4*>(s4)[i];
            float4 bn = make_float4(v.x*sc+sh, v.y*sc+sh, v.z*sc+sh, v.w*sc+sh);
            reinterpret_cast<float4*>(s4bn)[i] = bn;
            reinterpret_cast<float4*>(out)[i] =
                make_float4(tanhf(bn.x), tanhf(bn.y), tanhf(bn.z), tanhf(bn.w));
        }
    }
}

extern "C" void kernel_launch(void* const* d_in, const int* in_sizes, int n_in,
                              void* d_out, int out_size, void* d_ws, size_t ws_size,
                              hipStream_t stream)
{
    const float* z      = (const float*)d_in[0];
    const float* w1     = (const float*)d_in[1];
    const float* w2     = (const float*)d_in[2];
    const float* w3     = (const float*)d_in[3];
    const float* w4     = (const float*)d_in[4];
    const float* gamma2 = (const float*)d_in[5];
    const float* beta2  = (const float*)d_in[6];
    const float* gamma3 = (const float*)d_in[7];
    const float* beta3  = (const float*)d_in[8];
    const float* gamma4 = (const float*)d_in[9];
    const float* beta4  = (const float*)d_in[10];
    const float* gammaf = (const float*)d_in[11];
    const float* betaf  = (const float*)d_in[12];
    float* out = (float*)d_out;
    float* ws  = (float*)d_ws;

    // zero BN partial slots + barrier counters
    hipMemsetAsync(ws, 0, 7680 * sizeof(float), stream);

    fused_all<<<1024, 256, 0, stream>>>(
        z, w1, w2, w3, w4, gamma2, beta2, gamma3, beta3,
        gamma4, beta4, gammaf, betaf, out, ws);
}

// Round 8
// 172.196 us; speedup vs baseline: 4.2731x; 1.1038x over previous
//
#include <hip/hip_runtime.h>
#include <math.h>

// ---------------------------------------------------------------------------
// QuantumGenerator: ONE persistent kernel (1024 blocks x 256 threads,
// __launch_bounds__(256,4) => 4 blocks/CU x 256 CU co-resident) + one memset.
//
// KEY INVARIANT: block bid's phase-N+1 reads come EXACTLY from block bid's
// phase-N writes (batch stride 4096 floats, CPB*HW = 1024 at every layer) ->
// own stores visible via own L1/L2, NO cache maintenance needed.  Only
// cross-block data: BN partials (atomicAdd at LLC, read via relaxed agent
// atomic loads) and barrier state.
//
// Grid barrier v4 (v3's ~20us/barrier = poll storm: 1024 spinners on ONE
// root line every ~128cy serialized the LLC line and queued the arrival
// RMWs behind the polls):
//   arrival: 64 leaves (16 RMWs ea) -> 8 mids (8) -> root (8)  [parallel lines]
//   release: root-completer stores 64 per-leaf-group DONE flags (write-once
//            lines); spinners poll flag[bid&63]: 16 pollers/line, no storm.
//   relaxed everywhere; vmcnt-drain at syncthreads gives ordering; bounded
//   spin => co-residency failure terminates diagnosably.
//
// BN prologue v2: 256 threads cooperatively load the 2*CPB*32 partial slots
// (LLC atomic loads) + LDS-atomicAdd reduce -- replaces 64 scalar LLC loads
// PER THREAD (64-256x fewer LLC requests).
//
// Norm cancellation (exact): n^2=max(||x||^2,1e-18); d=(Vx)^2/max(S,1e-9*n^2)
// Per-block V build in LDS (cols 0-3 of the 8x8 unitary only).
// ---------------------------------------------------------------------------

#define NSLOT 32
#define NBLK  1024u

// ws float offsets
#define OFF_G2S 0        // 64*32
#define OFF_G2Q 2048     // 64*32
#define OFF_G3S 4096     // 16*32
#define OFF_G3Q 4608     // 16*32
#define OFF_G4S 5120     // 4*32
#define OFF_G4Q 5248     // 4*32
#define OFF_GFS 5376     // 1*32
#define OFF_GFQ 5408     // 1*32
#define OFF_CTR 5504     // 4 phases x 2192 uints (see gbar layout)
#define PHASE_STRIDE 2192
// memset covers [0 .. 5504 + 4*2192 = 14272) floats

__device__ __forceinline__ void gbar(unsigned* ctr, int phase)
{
    __syncthreads();   // vmcnt(0)+barrier: this block's stats atomics performed
    if (threadIdx.x == 0){
        unsigned* base  = ctr + phase*PHASE_STRIDE;
        const int  lf   = blockIdx.x & 63;
        unsigned* leaf  = base + (lf << 4);              // 64 lines, 16 arrivals ea
        unsigned* mid   = base + 1024 + ((lf >> 3) << 4);// 8 lines, 8 arrivals ea
        unsigned* root  = base + 1152;                   // 1 line, 8 arrivals
        unsigned* flags = base + 1168;                   // 64 write-once lines

        unsigned ol = __hip_atomic_fetch_add(leaf, 1u, __ATOMIC_RELAXED,
                                             __HIP_MEMORY_SCOPE_AGENT);
        if (ol == 15u){
            unsigned om = __hip_atomic_fetch_add(mid, 1u, __ATOMIC_RELAXED,
                                                 __HIP_MEMORY_SCOPE_AGENT);
            if (om == 7u){
                unsigned orr = __hip_atomic_fetch_add(root, 1u, __ATOMIC_RELAXED,
                                                      __HIP_MEMORY_SCOPE_AGENT);
                if (orr == 7u){
                    #pragma unroll
                    for (int i=0;i<64;i++)
                        __hip_atomic_store(flags + (i<<4), 1u, __ATOMIC_RELAXED,
                                           __HIP_MEMORY_SCOPE_AGENT);
                }
            }
        }
        unsigned* myflag = flags + (lf << 4);
        int spins = 0;
        while (__hip_atomic_load(myflag, __ATOMIC_RELAXED,
                                 __HIP_MEMORY_SCOPE_AGENT) == 0u){
            __builtin_amdgcn_s_sleep(2);
            if (++spins > 200000) break;    // failsafe: terminate, not hang
        }
        __atomic_signal_fence(__ATOMIC_SEQ_CST);  // compiler fence only
    }
    __syncthreads();
}

// read a BN partial slot from the coherent LLC (bypasses stale L1/L2)
__device__ __forceinline__ float llc_load(const float* p)
{
    return __hip_atomic_load(const_cast<float*>(p), __ATOMIC_RELAXED,
                             __HIP_MEMORY_SCOPE_AGENT);
}

template<int C, int H, int W, bool BN>
__device__ __forceinline__ void qcnn_phase(
    const float* __restrict__ x, const float* __restrict__ wl,
    const float* __restrict__ isum, const float* __restrict__ issq,
    const float* __restrict__ gamma, const float* __restrict__ beta,
    float invNin,
    float* __restrict__ out, float* __restrict__ osum, float* __restrict__ ossq,
    float* sBin, float* sV, float* sRed)
{
    constexpr int HW  = H*W;
    constexpr int P   = HW/4;                 // patches/channel: 4,16,64,256
    constexpr int OW  = W/2;
    constexpr int LP  = (P==4)?2:(P==16)?4:(P==64)?6:8;
    constexpr int LOW = (OW==2)?1:(OW==4)?2:(OW==8)?3:4;
    constexpr int CPB = 256/P;                // input channels per block
    constexpr int OCB = (CPB/4) < 1 ? 1 : (CPB/4);  // output BN bins per block
    constexpr int G   = (4*P < 64) ? 4*P : 64;      // lanes sharing one BN bin

    const int c0 = (blockIdx.x & 3) * CPB;

    // ---- build this block's V channels (cols 0-3 only) into LDS ----
    if (threadIdx.x < CPB*4){
        const int cl = threadIdx.x >> 2;      // local channel
        const int k  = threadIdx.x & 3;       // column 0..3
        const float* w = wl + (c0+cl)*18;
        float v[8];
        #pragma unroll
        for (int r=0;r<8;r++) v[r] = (r==k) ? 1.0f : 0.0f;
        for (int l=0;l<6;l++){
            float ca = cosf(0.5f*w[l*3+0]), sa = sinf(0.5f*w[l*3+0]);
            float cb = cosf(0.5f*w[l*3+1]), sb = sinf(0.5f*w[l*3+1]);
            float cc = cosf(0.5f*w[l*3+2]), sc_ = sinf(0.5f*w[l*3+2]);
            #pragma unroll
            for (int b=0;b<8;b+=2){ float xx=v[b], yy=v[b+1]; v[b]=cc*xx-sc_*yy; v[b+1]=sc_*xx+cc*yy; }
            #pragma unroll
            for (int g=0; g<8; g+=4)
                #pragma unroll
                for (int i=0;i<2;i++){ int a=g+i, b=g+i+2; float xx=v[a], yy=v[b]; v[a]=cb*xx-sb*yy; v[b]=sb*xx+cb*yy; }
            #pragma unroll
            for (int i=0;i<4;i++){ float xx=v[i], yy=v[i+4]; v[i]=ca*xx-sa*yy; v[i+4]=sa*xx+ca*yy; }
            // CNOT ring: new[perm[r]] = old[r]; perm = {0,5,7,2,3,6,4,1}
            float nv[8];
            nv[0]=v[0]; nv[5]=v[1]; nv[7]=v[2]; nv[2]=v[3];
            nv[3]=v[4]; nv[6]=v[5]; nv[4]=v[6]; nv[1]=v[7];
            #pragma unroll
            for (int r=0;r<8;r++) v[r]=nv[r];
        }
        #pragma unroll
        for (int r=0;r<4;r++) sV[cl*16 + r*4 + k] = v[r];   // U[r][k]
    }
    if (threadIdx.x < 2*OCB) sBin[threadIdx.x] = 0.0f;
    if constexpr (BN){ if (threadIdx.x < 2*CPB) sRed[threadIdx.x] = 0.0f; }
    __syncthreads();

    if constexpr (BN){
        // cooperative load of 2*CPB*32 partial slots from LLC -> LDS reduce
        constexpr int TOT = 2*CPB*NSLOT;     // 1024 / 256 / 64
        for (int i=threadIdx.x; i<TOT; i+=256){
            const int arr  = i / (CPB*NSLOT);
            const int rem  = i - arr*(CPB*NSLOT);
            const int cl   = rem >> 5;
            const int slot = rem & 31;
            float v = llc_load((arr ? issq : isum) + (c0+cl)*NSLOT + slot);
            atomicAdd(&sRed[arr*CPB + cl], v);
        }
        __syncthreads();
    }

    const int r   = ((blockIdx.x & 3) << 8) + threadIdx.x;
    const int c   = r >> LP;
    const int p   = r & (P-1);
    const int oh  = p >> LOW;
    const int ow  = p & (OW-1);
    const int oc0 = ((blockIdx.x & 3) << 8) >> (LP+2);
    const int ocl = (r >> (LP+2)) - oc0;
    const int xoff = c*HW + (oh*2)*W + (ow*2);
    const int ooff = c*HW + (p<<2);

    float sc = 0.0f, sh = 0.0f;
    if constexpr (BN){
        const int cl = c - c0;
        float s = sRed[cl], q = sRed[CPB+cl];
        float mean = s * invNin;
        float var  = q * invNin - mean*mean;
        float rinv = 1.0f / sqrtf(var + 1e-5f);
        sc = gamma[c] * rinv;
        sh = beta[c] - mean * sc;
    }
    const float4* Vc = reinterpret_cast<const float4*>(sV + (c-c0)*16);
    const float4 v0 = Vc[0], v1 = Vc[1], v2 = Vc[2], v3 = Vc[3];

    #pragma unroll
    for (int it=0; it<4; ++it){
        const int b = (it<<8) + (blockIdx.x>>2);
        const float* xb = x + ((size_t)b<<12) + xoff;
        float2 t0 = *reinterpret_cast<const float2*>(xb);
        float2 t1 = *reinterpret_cast<const float2*>(xb + W);
        float x0=t0.x, x1=t0.y, x2=t1.x, x3=t1.y;
        if constexpr (BN){
            x0 = fmaxf(x0*sc+sh, 0.0f);
            x1 = fmaxf(x1*sc+sh, 0.0f);
            x2 = fmaxf(x2*sc+sh, 0.0f);
            x3 = fmaxf(x3*sc+sh, 0.0f);
        }
        float nsq = x0*x0 + x1*x1 + x2*x2 + x3*x3;
        float q0 = v0.x*x0 + v0.y*x1 + v0.z*x2 + v0.w*x3;
        float q1 = v1.x*x0 + v1.y*x1 + v1.z*x2 + v1.w*x3;
        float q2 = v2.x*x0 + v2.y*x1 + v2.z*x2 + v2.w*x3;
        float q3 = v3.x*x0 + v3.y*x1 + v3.z*x2 + v3.w*x3;
        q0*=q0; q1*=q1; q2*=q2; q3*=q3;
        float s = q0+q1+q2+q3;
        float dinv = 1.0f / fmaxf(s, 1e-9f * fmaxf(nsq, 1e-18f));
        float d0=q0*dinv, d1=q1*dinv, d2=q2*dinv, d3=q3*dinv;
        *reinterpret_cast<float4*>(out + ((size_t)b<<12) + ooff) =
            make_float4(d0,d1,d2,d3);
        float ls  = d0+d1+d2+d3;
        float lss = d0*d0 + d1*d1 + d2*d2 + d3*d3;
        #pragma unroll
        for (int off=1; off<G; off<<=1){ ls += __shfl_xor(ls, off); lss += __shfl_xor(lss, off); }
        if ((threadIdx.x & (G-1)) == 0){
            atomicAdd(&sBin[ocl], ls);
            atomicAdd(&sBin[OCB + ocl], lss);
        }
    }
    __syncthreads();
    if (threadIdx.x < OCB){
        const int slot = (blockIdx.x >> 2) & (NSLOT-1);
        atomicAdd(&osum[(oc0+threadIdx.x)*NSLOT + slot], sBin[threadIdx.x]);
        atomicAdd(&ossq[(oc0+threadIdx.x)*NSLOT + slot], sBin[OCB+threadIdx.x]);
    }
}

__global__ __launch_bounds__(256, 4) void fused_all(
    const float* __restrict__ z,
    const float* __restrict__ w1, const float* __restrict__ w2,
    const float* __restrict__ w3, const float* __restrict__ w4,
    const float* __restrict__ gamma2, const float* __restrict__ beta2,
    const float* __restrict__ gamma3, const float* __restrict__ beta3,
    const float* __restrict__ gamma4, const float* __restrict__ beta4,
    const float* __restrict__ gammaf, const float* __restrict__ betaf,
    float* __restrict__ out, float* __restrict__ ws)
{
    __shared__ float sBin[32];
    __shared__ float sV[1024];                // up to 64 ch x 16 floats
    __shared__ float sRed[32];
    unsigned* ctr = reinterpret_cast<unsigned*>(ws + OFF_CTR);
    float* bufA = ws + 65536;                 // 4M floats (s1, then s3)
    float* bufB = bufA + 4194304;             // 4M floats (s2)
    float* s4   = out + 4194304;              // output slot 1
    float* s4bn = out + 8388608;              // output slot 2
    const int gtid = blockIdx.x*256 + threadIdx.x;

    // P1: L1  z(1024,256,4,4) -> s1(bufA); stats -> g2 (64 ch, N=65536)
    qcnn_phase<256,4,4,false>(z, w1, nullptr, nullptr, nullptr, nullptr, 0.0f,
                              bufA, ws+OFF_G2S, ws+OFF_G2Q, sBin, sV, sRed);
    gbar(ctr, 0);

    // P2: L2  relu(bn(s1)) -> s2(bufB); stats -> g3 (16 ch, N=262144)
    qcnn_phase<64,8,8,true>(bufA, w2, ws+OFF_G2S, ws+OFF_G2Q, gamma2, beta2,
                            1.0f/65536.0f, bufB, ws+OFF_G3S, ws+OFF_G3Q, sBin, sV, sRed);
    gbar(ctr, 1);

    // P3: L3 -> s3(bufA); stats -> g4 (4 ch, N=1048576)
    qcnn_phase<16,16,16,true>(bufB, w3, ws+OFF_G3S, ws+OFF_G3Q, gamma3, beta3,
                              1.0f/262144.0f, bufA, ws+OFF_G4S, ws+OFF_G4Q, sBin, sV, sRed);
    gbar(ctr, 2);

    // P4: L4 -> s4 (out slot 1); stats -> gf (1 ch, N=4194304)
    qcnn_phase<4,32,32,true>(bufA, w4, ws+OFF_G4S, ws+OFF_G4Q, gamma4, beta4,
                             1.0f/1048576.0f, s4, ws+OFF_GFS, ws+OFF_GFQ, sBin, sV, sRed);
    gbar(ctr, 3);

    // P5: final  s4_bn -> out slot 2, tanh -> out slot 0  (reads OWN s4 region)
    {
        // cooperative stat read: 64 lanes of wave 0 load the slots, shuffle-reduce
        float v = 0.0f;
        if (threadIdx.x < 64)
            v = llc_load(ws + (threadIdx.x < 32 ? OFF_GFS + threadIdx.x
                                                : OFF_GFQ + threadIdx.x - 32));
        #pragma unroll
        for (int off=1; off<32; off<<=1) v += __shfl_xor(v, off);
        if (threadIdx.x == 0)  sRed[0] = v;   // sum
        if (threadIdx.x == 32) sRed[1] = v;   // sum of squares
        __syncthreads();
        float s = sRed[0], q = sRed[1];
        float mean = s * (1.0f/4194304.0f);
        float var  = q * (1.0f/4194304.0f) - mean*mean;
        float rinv = 1.0f / sqrtf(var + 1e-5f);
        float sc = gammaf[0]*rinv;
        float sh = betaf[0] - mean*sc;
        #pragma unroll
        for (int k=0; k<4; ++k){
            int i = gtid + k*262144;                     // 1M float4s
            float4 vv = reinterpret_cast<const float4*>(s4)[i];
            float4 bn = make_float4(vv.x*sc+sh, vv.y*sc+sh, vv.z*sc+sh, vv.w*sc+sh);
            reinterpret_cast<float4*>(s4bn)[i] = bn;
            reinterpret_cast<float4*>(out)[i] =
                make_float4(tanhf(bn.x), tanhf(bn.y), tanhf(bn.z), tanhf(bn.w));
        }
    }
}

extern "C" void kernel_launch(void* const* d_in, const int* in_sizes, int n_in,
                              void* d_out, int out_size, void* d_ws, size_t ws_size,
                              hipStream_t stream)
{
    const float* z      = (const float*)d_in[0];
    const float* w1     = (const float*)d_in[1];
    const float* w2     = (const float*)d_in[2];
    const float* w3     = (const float*)d_in[3];
    const float* w4     = (const float*)d_in[4];
    const float* gamma2 = (const float*)d_in[5];
    const float* beta2  = (const float*)d_in[6];
    const float* gamma3 = (const float*)d_in[7];
    const float* beta3  = (const float*)d_in[8];
    const float* gamma4 = (const float*)d_in[9];
    const float* beta4  = (const float*)d_in[10];
    const float* gammaf = (const float*)d_in[11];
    const float* betaf  = (const float*)d_in[12];
    float* out = (float*)d_out;
    float* ws  = (float*)d_ws;

    // zero BN partial slots + barrier counters/flags
    hipMemsetAsync(ws, 0, (5504 + 4*PHASE_STRIDE) * sizeof(float), stream);

    fused_all<<<1024, 256, 0, stream>>>(
        z, w1, w2, w3, w4, gamma2, beta2, gamma3, beta3,
        gamma4, beta4, gammaf, betaf, out, ws);
}